// Round 6
// baseline (176.300 us; speedup 1.0000x reference)
//
#include <hip/hip_runtime.h>
#include <hip/hip_bf16.h>
#include <stdint.h>

typedef __attribute__((ext_vector_type(8))) short short8;
typedef __attribute__((ext_vector_type(4))) float f32x4;

#define MFMA16(a, b, c) __builtin_amdgcn_mfma_f32_16x16x32_bf16(a, b, c, 0, 0, 0)

__device__ __forceinline__ unsigned short f2bf_u(float f) {
  union { float f; uint32_t u; } x; x.f = f;
  uint32_t r = (x.u + 0x7fffu + ((x.u >> 16) & 1u)) >> 16;
  return (unsigned short)r;
}
__device__ __forceinline__ short f2bf(float f) { return (short)f2bf_u(f); }

__device__ __forceinline__ uint32_t pack_bf2(float lo, float hi) {
  __hip_bfloat162 h = __float22bfloat162_rn(make_float2(lo, hi));  // v_cvt_pk_bf16_f32
  union { __hip_bfloat162 h; uint32_t u; } c; c.h = h;
  return c.u;
}

// async global->LDS, 16B per lane. dest = wave-uniform base + lane*16.
__device__ __forceinline__ void gload_lds16(const void* g, void* lds) {
  __builtin_amdgcn_global_load_lds(
      (const __attribute__((address_space(1))) uint32_t*)(uintptr_t)g,
      (__attribute__((address_space(3))) uint32_t*)(uintptr_t)lds,
      16, 0, 0);
}

// ---------------- fp32 -> bf16 elementwise convert (X) ----------------
__global__ __launch_bounds__(256) void convert_bf16_kernel(
    const float* __restrict__ in, short* __restrict__ out, int n4) {
  int i = blockIdx.x * 256 + threadIdx.x;
  if (i >= n4) return;
  float4 v = reinterpret_cast<const float4*>(in)[i];
  short4 o;
  o.x = f2bf(v.x); o.y = f2bf(v.y); o.z = f2bf(v.z); o.w = f2bf(v.w);
  reinterpret_cast<short4*>(out)[i] = o;
}

// ------- all W (K x N fp32) -> WT (N x K bf16), one launch, grid (32,96) -------
__global__ __launch_bounds__(256) void transpose_all_kernel(
    const float* __restrict__ Wq, const float* __restrict__ Wk,
    const float* __restrict__ Wv, const float* __restrict__ Wo,
    short* __restrict__ WTQKV, short* __restrict__ WOT) {
  __shared__ float tile[32][33];
  int yb = blockIdx.y;
  const float* src; short* dst; int N; int yy;
  if (yb < 32)      { src = Wq; dst = WTQKV;                       N = 1024; yy = yb; }
  else if (yb < 48) { src = Wk; dst = WTQKV + (size_t)1024 * 1024; N = 512;  yy = yb - 32; }
  else if (yb < 64) { src = Wv; dst = WTQKV + (size_t)1536 * 1024; N = 512;  yy = yb - 48; }
  else              { src = Wo; dst = WOT;                         N = 1024; yy = yb - 64; }
  int k0 = blockIdx.x * 32, n0 = yy * 32;
  int tx = threadIdx.x, ty = threadIdx.y;  // (32,8)
#pragma unroll
  for (int i = 0; i < 4; ++i)
    tile[ty + 8 * i][tx] = src[(size_t)(k0 + ty + 8 * i) * N + n0 + tx];
  __syncthreads();
#pragma unroll
  for (int i = 0; i < 4; ++i)
    dst[(size_t)(n0 + ty + 8 * i) * 1024 + k0 + tx] = f2bf(tile[tx][ty + 8 * i]);
}

// ---------------- bf16 GEMM: C(MxN fp32) = A(MxK) * BT(NxK)^T ----------------
// 128x128 tile, BK=32, 4 waves, 2-barrier loop. XCD-bijective block swizzle.
__global__ __launch_bounds__(256) void gemm_bf16(
    const short* __restrict__ A, const short* __restrict__ BT,
    float* __restrict__ C, int M, int N, int K) {
  __shared__ short As[128 * 32];
  __shared__ short Bs[128 * 32];
  int wg = blockIdx.x + gridDim.x * blockIdx.y;      // nwg = 512 (divisible by 8)
  int lid = (wg & 7) * 64 + (wg >> 3);               // XCD gets 64 contiguous slots
  int m0 = (lid & 31) * 128, n0 = (lid >> 5) * 128;
  int t = threadIdx.x;
  int w = t >> 6, lane = t & 63;
  int wr = w >> 1, wc = w & 1;
  int lr = lane & 15, lg = lane >> 4;

  f32x4 acc[4][4] = {};

  for (int k0 = 0; k0 < K; k0 += 32) {
    __syncthreads();
#pragma unroll
    for (int i = 0; i < 2; ++i) {
      int c = t + 256 * i;
      gload_lds16(A + (size_t)(m0 + (c >> 2)) * K + k0 + (c & 3) * 8, &As[c * 8]);
      gload_lds16(BT + (size_t)(n0 + (c >> 2)) * K + k0 + (c & 3) * 8, &Bs[c * 8]);
    }
    __syncthreads();
    short8 af[4], bf[4];
#pragma unroll
    for (int mi = 0; mi < 4; ++mi)
      af[mi] = *(const short8*)&As[(wr * 64 + mi * 16 + lr) * 32 + lg * 8];
#pragma unroll
    for (int ni = 0; ni < 4; ++ni)
      bf[ni] = *(const short8*)&Bs[(wc * 64 + ni * 16 + lr) * 32 + lg * 8];
    __builtin_amdgcn_s_setprio(1);
#pragma unroll
    for (int mi = 0; mi < 4; ++mi)
#pragma unroll
      for (int ni = 0; ni < 4; ++ni)
        acc[mi][ni] = MFMA16(af[mi], bf[ni], acc[mi][ni]);
    __builtin_amdgcn_s_setprio(0);
  }
#pragma unroll
  for (int mi = 0; mi < 4; ++mi)
#pragma unroll
    for (int ni = 0; ni < 4; ++ni) {
      int row = m0 + wr * 64 + mi * 16 + lg * 4;
      int col = n0 + wc * 64 + ni * 16 + lr;
#pragma unroll
      for (int r = 0; r < 4; ++r)
        C[(size_t)(row + r) * N + col] = acc[mi][ni][r];
    }
}

// ---------------- 128x64-tile GEMM variant (out-proj) ----------------
__global__ __launch_bounds__(256) void gemm_bf16_bn64(
    const short* __restrict__ A, const short* __restrict__ BT,
    float* __restrict__ C, int M, int N, int K) {
  __shared__ short As[128 * 32];
  __shared__ short Bs[64 * 32];
  int wg = blockIdx.x + gridDim.x * blockIdx.y;      // nwg = 512
  int lid = (wg & 7) * 64 + (wg >> 3);
  int m0 = (lid & 31) * 128, n0 = (lid >> 5) * 64;
  int t = threadIdx.x;
  int w = t >> 6, lane = t & 63;
  int lr = lane & 15, lg = lane >> 4;

  f32x4 acc[2][4] = {};

  for (int k0 = 0; k0 < K; k0 += 32) {
    __syncthreads();
#pragma unroll
    for (int i = 0; i < 2; ++i) {
      int c = t + 256 * i;
      gload_lds16(A + (size_t)(m0 + (c >> 2)) * K + k0 + (c & 3) * 8, &As[c * 8]);
    }
    gload_lds16(BT + (size_t)(n0 + (t >> 2)) * K + k0 + (t & 3) * 8, &Bs[t * 8]);
    __syncthreads();
    short8 af[2], bf[4];
#pragma unroll
    for (int mi = 0; mi < 2; ++mi)
      af[mi] = *(const short8*)&As[(w * 32 + mi * 16 + lr) * 32 + lg * 8];
#pragma unroll
    for (int ni = 0; ni < 4; ++ni)
      bf[ni] = *(const short8*)&Bs[(ni * 16 + lr) * 32 + lg * 8];
    __builtin_amdgcn_s_setprio(1);
#pragma unroll
    for (int mi = 0; mi < 2; ++mi)
#pragma unroll
      for (int ni = 0; ni < 4; ++ni)
        acc[mi][ni] = MFMA16(af[mi], bf[ni], acc[mi][ni]);
    __builtin_amdgcn_s_setprio(0);
  }
#pragma unroll
  for (int mi = 0; mi < 2; ++mi)
#pragma unroll
    for (int ni = 0; ni < 4; ++ni) {
      int row = m0 + w * 32 + mi * 16 + lg * 4;
      int col = n0 + ni * 16 + lr;
#pragma unroll
      for (int r = 0; r < 4; ++r)
        C[(size_t)(row + r) * N + col] = acc[mi][ni][r];
    }
}

// ------------- RMSNorm + 2D RoPE + layout transform -------------
__global__ __launch_bounds__(256) void normrope_kernel(
    const float* __restrict__ QKV, const float* __restrict__ qg,
    const float* __restrict__ kg, const int* __restrict__ pos,
    short* __restrict__ Qp, short* __restrict__ Kp, short* __restrict__ Vt) {
  int wid = (blockIdx.x * 256 + threadIdx.x) >> 6;
  int lane = threadIdx.x & 63;
  int t = wid >> 5;      // token 0..4095
  int hh = wid & 31;     // 0-15 q, 16-23 k, 24-31 v
  int b = t >> 10, s = t & 1023;
  int col = (hh < 16) ? hh * 64 : (hh < 24) ? 1024 + (hh - 16) * 64 : 1536 + (hh - 24) * 64;
  float x = QKV[(size_t)t * 2048 + col + lane];
  float ss = x * x;
#pragma unroll
  for (int o = 1; o < 64; o <<= 1) ss += __shfl_xor(ss, o);
  float v = x * rsqrtf(ss * (1.0f / 64.0f) + 1e-6f);
  if (hh < 16) v *= 1.0f + qg[lane];
  else if (hh < 24) v *= 1.0f + kg[lane];
  if (hh < 24) {
    int fi = lane & 15;
    float p = (float)((lane < 32) ? pos[t * 2] : pos[t * 2 + 1]);
    float ang = p * exp2f((float)fi * -0.8304820237218405f);
    float sn, cs;
    __sincosf(ang, &sn, &cs);
    float partner = __shfl_xor(v, 16);
    v = ((lane & 31) < 16) ? (v * cs - partner * sn) : (v * cs + partner * sn);
  }
  short o = f2bf(v);
  if (hh < 16)      Qp[((size_t)((b * 16 + hh) * 1024 + s)) * 64 + lane] = o;
  else if (hh < 24) Kp[((size_t)((b * 8 + (hh - 16)) * 1024 + s)) * 64 + lane] = o;
  else              Vt[((size_t)((b * 8 + (hh - 24)) * 64 + lane)) * 1024 + s] = o;
}

// ------------- attention v5: pinned prefetch pipeline -------------
// Same structure as v4 (XCD remap, no-max softmax, 4-way split-KV) but:
// - __launch_bounds__(256,3): tell scheduler 3 waves/EU is target -> no
//   register-pressure rescheduling (which sank the prefetch loads in v4).
// - sched_barrier(0) after load-issue: loads cannot be moved below it.
// - V issued before next-K so PV's in-order vmcnt wait keeps K in flight.
__global__ __launch_bounds__(256, 3) void attn_kernel(
    const short* __restrict__ Qp, const short* __restrict__ Kp,
    const short* __restrict__ Vt, short* __restrict__ attn) {
  __shared__ float red[3][2][4][16][16];  // [w-1][mi][db][lr][lg*4+r]
  __shared__ float lred[3][2][16];        // [w-1][mi][lr]
  int wg = blockIdx.x;
  int xcd = wg & 7, slot = wg >> 3;          // hw: xcd = wg % 8
  int group = xcd * 8 + (slot >> 5);         // 0..63 = (b,h); 8 groups per xcd
  int qb = slot & 31;
  int b = group >> 4, h = group & 15;
  int hk = h >> 1;
  int w = threadIdx.x >> 6, lane = threadIdx.x & 63;
  int lr = lane & 15, lg = lane >> 4;
  int qt0 = qb * 32;

  const short* Qb = Qp + ((size_t)(b * 16 + h) * 1024) * 64;
  const short* Kb = Kp + ((size_t)(b * 8 + hk) * 1024) * 64 + (size_t)w * 256 * 64;
  const short* Vb = Vt + ((size_t)(b * 8 + hk) * 64) * 1024 + w * 256;

  short8 qf[2][2];
#pragma unroll
  for (int mi = 0; mi < 2; ++mi)
#pragma unroll
    for (int f = 0; f < 2; ++f)
      qf[mi][f] = *(const short8*)&Qb[(qt0 + mi * 16 + lr) * 64 + f * 32 + lg * 8];

  f32x4 acc[2][4] = {};   // [mi][db]: out^T[d=db*16+lg*4+r][q=qt0+mi*16+lr]
  float lsum[2] = {0.0f, 0.0f};

  short8 ka[4], kb_[4], vv[4];
#pragma unroll
  for (int kvb = 0; kvb < 2; ++kvb)
#pragma unroll
    for (int f = 0; f < 2; ++f)
      ka[kvb * 2 + f] = *(const short8*)&Kb[(kvb * 16 + lr) * 64 + f * 32 + lg * 8];

  auto body = [&](int it, short8 (&cur)[4], short8 (&nxt)[4]) {
    int kvo = it * 32;
    // V loads for THIS body: issued first (oldest in vmcnt order)
#pragma unroll
    for (int db = 0; db < 4; ++db)
      vv[db] = *(const short8*)&Vb[(size_t)(db * 16 + lr) * 1024 + kvo + lg * 8];
    // K prefetch for next body: issued second (stays in flight through PV wait)
    int kvn = ((it + 1 < 8) ? it + 1 : 7) * 32;
#pragma unroll
    for (int kvb = 0; kvb < 2; ++kvb)
#pragma unroll
      for (int f = 0; f < 2; ++f)
        nxt[kvb * 2 + f] = *(const short8*)&Kb[(kvn + kvb * 16 + lr) * 64 + f * 32 + lg * 8];
    // pin: no instruction (esp. these loads) may cross this point
    __builtin_amdgcn_sched_barrier(0);
    // S^T = K * Q^T using cur (loaded one body ago; wait is vmcnt(8))
    f32x4 sv[2][2];
    __builtin_amdgcn_s_setprio(1);
#pragma unroll
    for (int mi = 0; mi < 2; ++mi)
#pragma unroll
      for (int kvb = 0; kvb < 2; ++kvb) {
        f32x4 s = {};
        s = MFMA16(cur[kvb * 2 + 0], qf[mi][0], s);
        s = MFMA16(cur[kvb * 2 + 1], qf[mi][1], s);
        sv[mi][kvb] = s;
      }
    __builtin_amdgcn_s_setprio(0);
#pragma unroll
    for (int mi = 0; mi < 2; ++mi) {
      float p[2][4];
#pragma unroll
      for (int kvb = 0; kvb < 2; ++kvb)
#pragma unroll
        for (int r = 0; r < 4; ++r) {
          p[kvb][r] = __expf(sv[mi][kvb][r]);
          lsum[mi] += p[kvb][r];
        }
      uint32_t pk[2][2];
#pragma unroll
      for (int kvb = 0; kvb < 2; ++kvb)
#pragma unroll
        for (int wd = 0; wd < 2; ++wd)
          pk[kvb][wd] = pack_bf2(p[kvb][2 * wd], p[kvb][2 * wd + 1]);
      union { uint32_t u[4]; short8 s; } pb;
#pragma unroll
      for (int j2 = 0; j2 < 4; ++j2) {
        int src = (2 * (lg & 1) + (j2 >> 1)) * 16 + lr;
        uint32_t lo = (uint32_t)__shfl((int)pk[0][j2 & 1], src);
        uint32_t hi = (uint32_t)__shfl((int)pk[1][j2 & 1], src);
        pb.u[j2] = (lg >= 2) ? hi : lo;
      }
      __builtin_amdgcn_s_setprio(1);
#pragma unroll
      for (int db = 0; db < 4; ++db)
        acc[mi][db] = MFMA16(vv[db], pb.s, acc[mi][db]);  // waits vmcnt(4): K stays in flight
      __builtin_amdgcn_s_setprio(0);
    }
  };

#pragma unroll
  for (int it2 = 0; it2 < 8; it2 += 2) {
    body(it2, ka, kb_);
    body(it2 + 1, kb_, ka);
  }

  // ---- epilogue: reduce lsum over lg, merge 4 kv quarters, write ----
#pragma unroll
  for (int mi = 0; mi < 2; ++mi) {
    lsum[mi] += __shfl_xor(lsum[mi], 16);
    lsum[mi] += __shfl_xor(lsum[mi], 32);
  }
  if (w > 0) {
#pragma unroll
    for (int mi = 0; mi < 2; ++mi) {
#pragma unroll
      for (int db = 0; db < 4; ++db)
        *(f32x4*)&red[w - 1][mi][db][lr][lg * 4] = acc[mi][db];
      if (lg == 0) lred[w - 1][mi][lr] = lsum[mi];
    }
  }
  __syncthreads();
  if (w == 0) {
#pragma unroll
    for (int mi = 0; mi < 2; ++mi) {
      float lt = lsum[mi] + lred[0][mi][lr] + lred[1][mi][lr] + lred[2][mi][lr];
      float inv = 1.0f / lt;
      size_t rowbase = ((size_t)(b * 1024 + qt0 + mi * 16 + lr)) * 1024 + h * 64;
#pragma unroll
      for (int db = 0; db < 4; ++db) {
        f32x4 o = acc[mi][db];
#pragma unroll
        for (int s2 = 0; s2 < 3; ++s2)
          o += *(const f32x4*)&red[s2][mi][db][lr][lg * 4];
        uint32_t w0 = pack_bf2(o[0] * inv, o[1] * inv);
        uint32_t w1 = pack_bf2(o[2] * inv, o[3] * inv);
        uint32_t* pp = (uint32_t*)&attn[rowbase + db * 16 + lg * 4];
        pp[0] = w0;
        pp[1] = w1;
      }
    }
  }
}

extern "C" void kernel_launch(void* const* d_in, const int* in_sizes, int n_in,
                              void* d_out, int out_size, void* d_ws, size_t ws_size,
                              hipStream_t stream) {
  const float* X  = (const float*)d_in[0];
  const float* Wq = (const float*)d_in[1];
  const float* Wk = (const float*)d_in[2];
  const float* Wv = (const float*)d_in[3];
  const float* Wo = (const float*)d_in[4];
  const float* qg = (const float*)d_in[5];
  const float* kg = (const float*)d_in[6];
  const int* pos  = (const int*)d_in[7];
  float* out = (float*)d_out;

  char* ws = (char*)d_ws;
  short* XB    = (short*)(ws);                       // 8 MB  X bf16
  short* WTQKV = (short*)(ws + ((size_t)8 << 20));   // 4 MB  [Wq^T;Wk^T;Wv^T]
  short* WOT   = (short*)(ws + ((size_t)12 << 20));  // 2 MB  Wo^T
  float* QKV   = (float*)(ws + ((size_t)14 << 20));  // 32 MB (4096x2048 fp32)
  short* QP    = (short*)(ws + ((size_t)46 << 20));  // 8 MB
  short* KP    = (short*)(ws + ((size_t)54 << 20));  // 4 MB
  short* VT    = (short*)(ws + ((size_t)58 << 20));  // 4 MB
  short* ATT   = (short*)(ws + ((size_t)62 << 20));  // 8 MB

  convert_bf16_kernel<<<4096, 256, 0, stream>>>(X, XB, 1048576);
  transpose_all_kernel<<<dim3(32, 96), dim3(32, 8), 0, stream>>>(Wq, Wk, Wv, Wo, WTQKV, WOT);

  gemm_bf16<<<dim3(32, 16), 256, 0, stream>>>(XB, WTQKV, QKV, 4096, 2048, 1024);
  normrope_kernel<<<32768, 256, 0, stream>>>(QKV, qg, kg, pos, QP, KP, VT);
  attn_kernel<<<2048, 256, 0, stream>>>(QP, KP, VT, ATT);
  gemm_bf16_bn64<<<dim3(32, 16), 256, 0, stream>>>(ATT, WOT, out, 4096, 1024, 1024);
}

// Round 7
// 152.384 us; speedup vs baseline: 1.1569x; 1.1569x over previous
//
#include <hip/hip_runtime.h>
#include <hip/hip_bf16.h>
#include <stdint.h>

typedef __attribute__((ext_vector_type(8))) short short8;
typedef __attribute__((ext_vector_type(4))) float f32x4;

#define MFMA16(a, b, c) __builtin_amdgcn_mfma_f32_16x16x32_bf16(a, b, c, 0, 0, 0)

__device__ __forceinline__ unsigned short f2bf_u(float f) {
  union { float f; uint32_t u; } x; x.f = f;
  uint32_t r = (x.u + 0x7fffu + ((x.u >> 16) & 1u)) >> 16;
  return (unsigned short)r;
}
__device__ __forceinline__ short f2bf(float f) { return (short)f2bf_u(f); }

__device__ __forceinline__ uint32_t pack_bf2(float lo, float hi) {
  __hip_bfloat162 h = __float22bfloat162_rn(make_float2(lo, hi));  // v_cvt_pk_bf16_f32
  union { __hip_bfloat162 h; uint32_t u; } c; c.h = h;
  return c.u;
}

// async global->LDS, 16B per lane. dest = wave-uniform base + lane*16.
__device__ __forceinline__ void gload_lds16(const void* g, void* lds) {
  __builtin_amdgcn_global_load_lds(
      (const __attribute__((address_space(1))) uint32_t*)(uintptr_t)g,
      (__attribute__((address_space(3))) uint32_t*)(uintptr_t)lds,
      16, 0, 0);
}

// ---------------- fp32 -> bf16 elementwise convert (X) ----------------
__global__ __launch_bounds__(256) void convert_bf16_kernel(
    const float* __restrict__ in, short* __restrict__ out, int n4) {
  int i = blockIdx.x * 256 + threadIdx.x;
  if (i >= n4) return;
  float4 v = reinterpret_cast<const float4*>(in)[i];
  short4 o;
  o.x = f2bf(v.x); o.y = f2bf(v.y); o.z = f2bf(v.z); o.w = f2bf(v.w);
  reinterpret_cast<short4*>(out)[i] = o;
}

// ------- all W (K x N fp32) -> WT (N x K bf16), one launch, grid (32,96) -------
__global__ __launch_bounds__(256) void transpose_all_kernel(
    const float* __restrict__ Wq, const float* __restrict__ Wk,
    const float* __restrict__ Wv, const float* __restrict__ Wo,
    short* __restrict__ WTQKV, short* __restrict__ WOT) {
  __shared__ float tile[32][33];
  int yb = blockIdx.y;
  const float* src; short* dst; int N; int yy;
  if (yb < 32)      { src = Wq; dst = WTQKV;                       N = 1024; yy = yb; }
  else if (yb < 48) { src = Wk; dst = WTQKV + (size_t)1024 * 1024; N = 512;  yy = yb - 32; }
  else if (yb < 64) { src = Wv; dst = WTQKV + (size_t)1536 * 1024; N = 512;  yy = yb - 48; }
  else              { src = Wo; dst = WOT;                         N = 1024; yy = yb - 64; }
  int k0 = blockIdx.x * 32, n0 = yy * 32;
  int tx = threadIdx.x, ty = threadIdx.y;  // (32,8)
#pragma unroll
  for (int i = 0; i < 4; ++i)
    tile[ty + 8 * i][tx] = src[(size_t)(k0 + ty + 8 * i) * N + n0 + tx];
  __syncthreads();
#pragma unroll
  for (int i = 0; i < 4; ++i)
    dst[(size_t)(n0 + ty + 8 * i) * 1024 + k0 + tx] = f2bf(tile[tx][ty + 8 * i]);
}

// ---------------- bf16 GEMM: C(MxN fp32) = A(MxK) * BT(NxK)^T ----------------
// 128x128 tile, BK=32, 4 waves, 2-barrier loop. XCD-bijective block swizzle.
__global__ __launch_bounds__(256) void gemm_bf16(
    const short* __restrict__ A, const short* __restrict__ BT,
    float* __restrict__ C, int M, int N, int K) {
  __shared__ short As[128 * 32];
  __shared__ short Bs[128 * 32];
  int wg = blockIdx.x + gridDim.x * blockIdx.y;      // nwg = 512 (divisible by 8)
  int lid = (wg & 7) * 64 + (wg >> 3);               // XCD gets 64 contiguous slots
  int m0 = (lid & 31) * 128, n0 = (lid >> 5) * 128;
  int t = threadIdx.x;
  int w = t >> 6, lane = t & 63;
  int wr = w >> 1, wc = w & 1;
  int lr = lane & 15, lg = lane >> 4;

  f32x4 acc[4][4] = {};

  for (int k0 = 0; k0 < K; k0 += 32) {
    __syncthreads();
#pragma unroll
    for (int i = 0; i < 2; ++i) {
      int c = t + 256 * i;
      gload_lds16(A + (size_t)(m0 + (c >> 2)) * K + k0 + (c & 3) * 8, &As[c * 8]);
      gload_lds16(BT + (size_t)(n0 + (c >> 2)) * K + k0 + (c & 3) * 8, &Bs[c * 8]);
    }
    __syncthreads();
    short8 af[4], bf[4];
#pragma unroll
    for (int mi = 0; mi < 4; ++mi)
      af[mi] = *(const short8*)&As[(wr * 64 + mi * 16 + lr) * 32 + lg * 8];
#pragma unroll
    for (int ni = 0; ni < 4; ++ni)
      bf[ni] = *(const short8*)&Bs[(wc * 64 + ni * 16 + lr) * 32 + lg * 8];
    __builtin_amdgcn_s_setprio(1);
#pragma unroll
    for (int mi = 0; mi < 4; ++mi)
#pragma unroll
      for (int ni = 0; ni < 4; ++ni)
        acc[mi][ni] = MFMA16(af[mi], bf[ni], acc[mi][ni]);
    __builtin_amdgcn_s_setprio(0);
  }
#pragma unroll
  for (int mi = 0; mi < 4; ++mi)
#pragma unroll
    for (int ni = 0; ni < 4; ++ni) {
      int row = m0 + wr * 64 + mi * 16 + lg * 4;
      int col = n0 + wc * 64 + ni * 16 + lr;
#pragma unroll
      for (int r = 0; r < 4; ++r)
        C[(size_t)(row + r) * N + col] = acc[mi][ni][r];
    }
}

// ---------------- 128x64-tile GEMM variant (out-proj) ----------------
__global__ __launch_bounds__(256) void gemm_bf16_bn64(
    const short* __restrict__ A, const short* __restrict__ BT,
    float* __restrict__ C, int M, int N, int K) {
  __shared__ short As[128 * 32];
  __shared__ short Bs[64 * 32];
  int wg = blockIdx.x + gridDim.x * blockIdx.y;      // nwg = 512
  int lid = (wg & 7) * 64 + (wg >> 3);
  int m0 = (lid & 31) * 128, n0 = (lid >> 5) * 64;
  int t = threadIdx.x;
  int w = t >> 6, lane = t & 63;
  int lr = lane & 15, lg = lane >> 4;

  f32x4 acc[2][4] = {};

  for (int k0 = 0; k0 < K; k0 += 32) {
    __syncthreads();
#pragma unroll
    for (int i = 0; i < 2; ++i) {
      int c = t + 256 * i;
      gload_lds16(A + (size_t)(m0 + (c >> 2)) * K + k0 + (c & 3) * 8, &As[c * 8]);
    }
    gload_lds16(BT + (size_t)(n0 + (t >> 2)) * K + k0 + (t & 3) * 8, &Bs[t * 8]);
    __syncthreads();
    short8 af[2], bf[4];
#pragma unroll
    for (int mi = 0; mi < 2; ++mi)
      af[mi] = *(const short8*)&As[(w * 32 + mi * 16 + lr) * 32 + lg * 8];
#pragma unroll
    for (int ni = 0; ni < 4; ++ni)
      bf[ni] = *(const short8*)&Bs[(ni * 16 + lr) * 32 + lg * 8];
    __builtin_amdgcn_s_setprio(1);
#pragma unroll
    for (int mi = 0; mi < 2; ++mi)
#pragma unroll
      for (int ni = 0; ni < 4; ++ni)
        acc[mi][ni] = MFMA16(af[mi], bf[ni], acc[mi][ni]);
    __builtin_amdgcn_s_setprio(0);
  }
#pragma unroll
  for (int mi = 0; mi < 2; ++mi)
#pragma unroll
    for (int ni = 0; ni < 4; ++ni) {
      int row = m0 + w * 32 + mi * 16 + lg * 4;
      int col = n0 + ni * 16 + lr;
#pragma unroll
      for (int r = 0; r < 4; ++r)
        C[(size_t)(row + r) * N + col] = acc[mi][ni][r];
    }
}

// ------------- RMSNorm + 2D RoPE + layout transform -------------
__global__ __launch_bounds__(256) void normrope_kernel(
    const float* __restrict__ QKV, const float* __restrict__ qg,
    const float* __restrict__ kg, const int* __restrict__ pos,
    short* __restrict__ Qp, short* __restrict__ Kp, short* __restrict__ Vt) {
  int wid = (blockIdx.x * 256 + threadIdx.x) >> 6;
  int lane = threadIdx.x & 63;
  int t = wid >> 5;      // token 0..4095
  int hh = wid & 31;     // 0-15 q, 16-23 k, 24-31 v
  int b = t >> 10, s = t & 1023;
  int col = (hh < 16) ? hh * 64 : (hh < 24) ? 1024 + (hh - 16) * 64 : 1536 + (hh - 24) * 64;
  float x = QKV[(size_t)t * 2048 + col + lane];
  float ss = x * x;
#pragma unroll
  for (int o = 1; o < 64; o <<= 1) ss += __shfl_xor(ss, o);
  float v = x * rsqrtf(ss * (1.0f / 64.0f) + 1e-6f);
  if (hh < 16) v *= 1.0f + qg[lane];
  else if (hh < 24) v *= 1.0f + kg[lane];
  if (hh < 24) {
    int fi = lane & 15;
    float p = (float)((lane < 32) ? pos[t * 2] : pos[t * 2 + 1]);
    float ang = p * exp2f((float)fi * -0.8304820237218405f);
    float sn, cs;
    __sincosf(ang, &sn, &cs);
    float partner = __shfl_xor(v, 16);
    v = ((lane & 31) < 16) ? (v * cs - partner * sn) : (v * cs + partner * sn);
  }
  short o = f2bf(v);
  if (hh < 16)      Qp[((size_t)((b * 16 + hh) * 1024 + s)) * 64 + lane] = o;
  else if (hh < 24) Kp[((size_t)((b * 8 + (hh - 16)) * 1024 + s)) * 64 + lane] = o;
  else              Vt[((size_t)((b * 8 + (hh - 24)) * 64 + lane)) * 1024 + s] = o;
}

// ------------- attention v6: LDS-staged K/V (DMA), no VGPR prefetch -------------
// grid 1024 = B*H*(S/64), XCD-pinned per (b,h). 4 waves; wave w owns q rows
// [qb*64+w*16, +16) over the FULL kv range (no split, no merge). Per 64-kv
// tile: global_load_lds K (2x[64][32] subtiles) + V^T (2x[64][32]), m97-style
// 2-barrier loop, then pure LDS-fragment MFMA + no-max softmax + PV.
// DMA staging needs no VGPRs -> register allocator cannot sink the pipeline.
__global__ __launch_bounds__(256) void attn_kernel(
    const short* __restrict__ Qp, const short* __restrict__ Kp,
    const short* __restrict__ Vt, short* __restrict__ attn) {
  __shared__ short Ks[2 * 64 * 32];   // [f][kv][32] : K[kv][f*32..+32]
  __shared__ short Vs[2 * 64 * 32];   // [kvs][d][32]: V^T[d][kvs*32..+32]
  int wg = blockIdx.x;
  int xcd = wg & 7, slot = wg >> 3;        // 0..127
  int group = xcd * 8 + (slot >> 4);       // 0..63 = (b,h); 8 groups/XCD
  int qb = slot & 15;
  int b = group >> 4, h = group & 15;
  int hk = h >> 1;
  int t = threadIdx.x;
  int w = t >> 6, lane = t & 63;
  int lr = lane & 15, lg = lane >> 4;
  int q0 = qb * 64 + w * 16;

  const short* Qb = Qp + ((size_t)(b * 16 + h) * 1024) * 64;
  const short* Kb = Kp + ((size_t)(b * 8 + hk) * 1024) * 64;
  const short* Vb = Vt + ((size_t)(b * 8 + hk) * 64) * 1024;

  short8 qf[2];
#pragma unroll
  for (int f = 0; f < 2; ++f)
    qf[f] = *(const short8*)&Qb[(q0 + lr) * 64 + f * 32 + lg * 8];

  f32x4 acc[4] = {};   // [db]: out^T[d=db*16+lg*4+r][q=lr]
  float lsum = 0.0f;

  for (int kt = 0; kt < 16; ++kt) {
    int kv0 = kt * 64;
    __syncthreads();   // all waves done reading previous tile
    // stage K tile: 512 16B-chunks; chunk q -> Ks[q*8]; src K[kv0+kv][f*32+c*8]
#pragma unroll
    for (int i = 0; i < 2; ++i) {
      int q = t + 256 * i;
      int f = q >> 8, rem = q & 255, kv = rem >> 2, c = rem & 3;
      gload_lds16(Kb + (size_t)(kv0 + kv) * 64 + f * 32 + c * 8, &Ks[q * 8]);
    }
    // stage V^T tile: chunk q -> Vs[q*8]; src V^T[d][kv0+kvs*32+c*8]
#pragma unroll
    for (int i = 0; i < 2; ++i) {
      int q = t + 256 * i;
      int kvs = q >> 8, rem = q & 255, d = rem >> 2, c = rem & 3;
      gload_lds16(Vb + (size_t)d * 1024 + kv0 + kvs * 32 + c * 8, &Vs[q * 8]);
    }
    __syncthreads();   // vmcnt(0) drain: tile ready
    // S^T = K * Q^T : lane holds S[q=lr][kv0 + kvb*16 + lg*4 + r]
    f32x4 sv[4];
    __builtin_amdgcn_s_setprio(1);
#pragma unroll
    for (int kvb = 0; kvb < 4; ++kvb) {
      short8 a0 = *(const short8*)&Ks[(kvb * 16 + lr) * 32 + lg * 8];
      short8 a1 = *(const short8*)&Ks[2048 + (kvb * 16 + lr) * 32 + lg * 8];
      f32x4 s = {};
      s = MFMA16(a0, qf[0], s);
      s = MFMA16(a1, qf[1], s);
      sv[kvb] = s;
    }
    __builtin_amdgcn_s_setprio(0);
    // exp (no max subtraction: |logits| <~ 44 after rms-norm) + pack to bf16
    uint32_t pk[4][2];
#pragma unroll
    for (int kvb = 0; kvb < 4; ++kvb) {
      float p0 = __expf(sv[kvb][0]), p1 = __expf(sv[kvb][1]);
      float p2 = __expf(sv[kvb][2]), p3 = __expf(sv[kvb][3]);
      lsum += (p0 + p1) + (p2 + p3);
      pk[kvb][0] = pack_bf2(p0, p1);
      pk[kvb][1] = pack_bf2(p2, p3);
    }
    // PV per 32-kv step: build B-frag of P^T via shuffles, MFMA with V^T frags
#pragma unroll
    for (int kvs = 0; kvs < 2; ++kvs) {
      union { uint32_t u[4]; short8 s; } pb;
#pragma unroll
      for (int j2 = 0; j2 < 4; ++j2) {
        int src = (2 * (lg & 1) + (j2 >> 1)) * 16 + lr;
        uint32_t lo = (uint32_t)__shfl((int)pk[kvs * 2 + 0][j2 & 1], src);
        uint32_t hi = (uint32_t)__shfl((int)pk[kvs * 2 + 1][j2 & 1], src);
        pb.u[j2] = (lg >= 2) ? hi : lo;
      }
      __builtin_amdgcn_s_setprio(1);
#pragma unroll
      for (int db = 0; db < 4; ++db) {
        short8 vf = *(const short8*)&Vs[kvs * 2048 + (db * 16 + lr) * 32 + lg * 8];
        acc[db] = MFMA16(vf, pb.s, acc[db]);
      }
      __builtin_amdgcn_s_setprio(0);
    }
  }

  // ---- epilogue: reduce lsum over lg, scale, write ----
  lsum += __shfl_xor(lsum, 16);
  lsum += __shfl_xor(lsum, 32);
  float inv = 1.0f / lsum;
  size_t rowbase = ((size_t)(b * 1024 + q0 + lr)) * 1024 + h * 64;
#pragma unroll
  for (int db = 0; db < 4; ++db) {
    uint32_t w0 = pack_bf2(acc[db][0] * inv, acc[db][1] * inv);
    uint32_t w1 = pack_bf2(acc[db][2] * inv, acc[db][3] * inv);
    uint32_t* pp = (uint32_t*)&attn[rowbase + db * 16 + lg * 4];
    pp[0] = w0;
    pp[1] = w1;
  }
}

extern "C" void kernel_launch(void* const* d_in, const int* in_sizes, int n_in,
                              void* d_out, int out_size, void* d_ws, size_t ws_size,
                              hipStream_t stream) {
  const float* X  = (const float*)d_in[0];
  const float* Wq = (const float*)d_in[1];
  const float* Wk = (const float*)d_in[2];
  const float* Wv = (const float*)d_in[3];
  const float* Wo = (const float*)d_in[4];
  const float* qg = (const float*)d_in[5];
  const float* kg = (const float*)d_in[6];
  const int* pos  = (const int*)d_in[7];
  float* out = (float*)d_out;

  char* ws = (char*)d_ws;
  short* XB    = (short*)(ws);                       // 8 MB  X bf16
  short* WTQKV = (short*)(ws + ((size_t)8 << 20));   // 4 MB  [Wq^T;Wk^T;Wv^T]
  short* WOT   = (short*)(ws + ((size_t)12 << 20));  // 2 MB  Wo^T
  float* QKV   = (float*)(ws + ((size_t)14 << 20));  // 32 MB (4096x2048 fp32)
  short* QP    = (short*)(ws + ((size_t)46 << 20));  // 8 MB
  short* KP    = (short*)(ws + ((size_t)54 << 20));  // 4 MB
  short* VT    = (short*)(ws + ((size_t)58 << 20));  // 4 MB
  short* ATT   = (short*)(ws + ((size_t)62 << 20));  // 8 MB

  convert_bf16_kernel<<<4096, 256, 0, stream>>>(X, XB, 1048576);
  transpose_all_kernel<<<dim3(32, 96), dim3(32, 8), 0, stream>>>(Wq, Wk, Wv, Wo, WTQKV, WOT);

  gemm_bf16<<<dim3(32, 16), 256, 0, stream>>>(XB, WTQKV, QKV, 4096, 2048, 1024);
  normrope_kernel<<<32768, 256, 0, stream>>>(QKV, qg, kg, pos, QP, KP, VT);
  attn_kernel<<<1024, 256, 0, stream>>>(QP, KP, VT, ATT);
  gemm_bf16_bn64<<<dim3(32, 16), 256, 0, stream>>>(ATT, WOT, out, 4096, 1024, 1024);
}

// Round 8
// 102.385 us; speedup vs baseline: 1.7219x; 1.4883x over previous
//
#include <hip/hip_runtime.h>
#include <hip/hip_bf16.h>
#include <stdint.h>

typedef __attribute__((ext_vector_type(8))) short short8;
typedef __attribute__((ext_vector_type(4))) float f32x4;

#define MFMA16(a, b, c) __builtin_amdgcn_mfma_f32_16x16x32_bf16(a, b, c, 0, 0, 0)

__device__ __forceinline__ unsigned short f2bf_u(float f) {
  union { float f; uint32_t u; } x; x.f = f;
  uint32_t r = (x.u + 0x7fffu + ((x.u >> 16) & 1u)) >> 16;
  return (unsigned short)r;
}
__device__ __forceinline__ short f2bf(float f) { return (short)f2bf_u(f); }

__device__ __forceinline__ uint32_t pack_bf2(float lo, float hi) {
  __hip_bfloat162 h = __float22bfloat162_rn(make_float2(lo, hi));  // v_cvt_pk_bf16_f32
  union { __hip_bfloat162 h; uint32_t u; } c; c.h = h;
  return c.u;
}

// async global->LDS, 16B per lane. dest = wave-uniform base + lane*16.
__device__ __forceinline__ void gload_lds16(const void* g, void* lds) {
  __builtin_amdgcn_global_load_lds(
      (const __attribute__((address_space(1))) uint32_t*)(uintptr_t)g,
      (__attribute__((address_space(3))) uint32_t*)(uintptr_t)lds,
      16, 0, 0);
}

// ---------------- fp32 -> bf16 elementwise convert (X) ----------------
__global__ __launch_bounds__(256) void convert_bf16_kernel(
    const float* __restrict__ in, short* __restrict__ out, int n4) {
  int i = blockIdx.x * 256 + threadIdx.x;
  if (i >= n4) return;
  float4 v = reinterpret_cast<const float4*>(in)[i];
  short4 o;
  o.x = f2bf(v.x); o.y = f2bf(v.y); o.z = f2bf(v.z); o.w = f2bf(v.w);
  reinterpret_cast<short4*>(out)[i] = o;
}

// ------- all W (K x N fp32) -> WT (N x K bf16), one launch, grid (32,96) -------
__global__ __launch_bounds__(256) void transpose_all_kernel(
    const float* __restrict__ Wq, const float* __restrict__ Wk,
    const float* __restrict__ Wv, const float* __restrict__ Wo,
    short* __restrict__ WTQKV, short* __restrict__ WOT) {
  __shared__ float tile[32][33];
  int yb = blockIdx.y;
  const float* src; short* dst; int N; int yy;
  if (yb < 32)      { src = Wq; dst = WTQKV;                       N = 1024; yy = yb; }
  else if (yb < 48) { src = Wk; dst = WTQKV + (size_t)1024 * 1024; N = 512;  yy = yb - 32; }
  else if (yb < 64) { src = Wv; dst = WTQKV + (size_t)1536 * 1024; N = 512;  yy = yb - 48; }
  else              { src = Wo; dst = WOT;                         N = 1024; yy = yb - 64; }
  int k0 = blockIdx.x * 32, n0 = yy * 32;
  int tx = threadIdx.x, ty = threadIdx.y;  // (32,8)
#pragma unroll
  for (int i = 0; i < 4; ++i)
    tile[ty + 8 * i][tx] = src[(size_t)(k0 + ty + 8 * i) * N + n0 + tx];
  __syncthreads();
#pragma unroll
  for (int i = 0; i < 4; ++i)
    dst[(size_t)(n0 + ty + 8 * i) * 1024 + k0 + tx] = f2bf(tile[tx][ty + 8 * i]);
}

// -------- GEMM1 fused: QKV = XB @ WTQKV^T, + RMSNorm + 2D RoPE + layouts --------
// 128x128 tile, BK=32, 4 waves. Wave's 64-col span == ONE head-vector group:
// d = ni*16+lr, RoPE pairs (d,d+16) are same-lane adjacent-ni; fi = lr.
// Writes Qp (b,h,s,d), Kp (b,hk,s,d), Vt (b,hk,d,s) bf16 directly.
__global__ __launch_bounds__(256) void gemm_qkv_fused(
    const short* __restrict__ A, const short* __restrict__ BT,
    const float* __restrict__ qg, const float* __restrict__ kg,
    const int* __restrict__ pos,
    short* __restrict__ Qp, short* __restrict__ Kp, short* __restrict__ Vt) {
  const int K = 1024;
  __shared__ short As[128 * 32];
  __shared__ short Bs[128 * 32];
  int wg = blockIdx.x + gridDim.x * blockIdx.y;      // nwg = 512
  int lid = (wg & 7) * 64 + (wg >> 3);               // XCD-contiguous
  int m0 = (lid & 31) * 128, n0 = (lid >> 5) * 128;
  int t = threadIdx.x;
  int w = t >> 6, lane = t & 63;
  int wr = w >> 1, wc = w & 1;
  int lr = lane & 15, lg = lane >> 4;

  f32x4 acc[4][4] = {};

  for (int k0 = 0; k0 < K; k0 += 32) {
    __syncthreads();
#pragma unroll
    for (int i = 0; i < 2; ++i) {
      int c = t + 256 * i;
      gload_lds16(A + (size_t)(m0 + (c >> 2)) * K + k0 + (c & 3) * 8, &As[c * 8]);
      gload_lds16(BT + (size_t)(n0 + (c >> 2)) * K + k0 + (c & 3) * 8, &Bs[c * 8]);
    }
    __syncthreads();
    short8 af[4], bf[4];
#pragma unroll
    for (int mi = 0; mi < 4; ++mi)
      af[mi] = *(const short8*)&As[(wr * 64 + mi * 16 + lr) * 32 + lg * 8];
#pragma unroll
    for (int ni = 0; ni < 4; ++ni)
      bf[ni] = *(const short8*)&Bs[(wc * 64 + ni * 16 + lr) * 32 + lg * 8];
    __builtin_amdgcn_s_setprio(1);
#pragma unroll
    for (int mi = 0; mi < 4; ++mi)
#pragma unroll
      for (int ni = 0; ni < 4; ++ni)
        acc[mi][ni] = MFMA16(af[mi], bf[ni], acc[mi][ni]);
    __builtin_amdgcn_s_setprio(0);
  }

  // ---- fused epilogue ----
  int g = (n0 >> 6) + wc;        // 0..31: head-vector group. <16 Q, <24 K, else V
  int row0 = m0 + wr * 64;
  const int2* posv = (const int2*)pos;

  if (g < 24) {
    // Q or K: rms-norm * (1+gamma), 2D RoPE, write [*, s, d] layout
    const float* gsrc = (g < 16) ? qg : kg;
    short* dst = (g < 16) ? Qp : Kp;
    int nh = (g < 16) ? 16 : 8;
    int h = (g < 16) ? g : g - 16;
    float gam[4];
#pragma unroll
    for (int ni = 0; ni < 4; ++ni) gam[ni] = 1.0f + gsrc[ni * 16 + lr];
    float invf = exp2f((float)lr * -0.8304820237218405f);  // 10000^(-lr/16)
#pragma unroll
    for (int mi = 0; mi < 4; ++mi) {
      f32x4 ss = acc[mi][0] * acc[mi][0];
#pragma unroll
      for (int ni = 1; ni < 4; ++ni) ss += acc[mi][ni] * acc[mi][ni];
#pragma unroll
      for (int m2 = 1; m2 < 16; m2 <<= 1)
#pragma unroll
        for (int r = 0; r < 4; ++r) ss[r] += __shfl_xor(ss[r], m2);
#pragma unroll
      for (int r = 0; r < 4; ++r) {
        int row = row0 + mi * 16 + lg * 4 + r;
        float inv = rsqrtf(ss[r] * 0.015625f + 1e-6f);
        float v0 = acc[mi][0][r] * inv * gam[0];
        float v1 = acc[mi][1][r] * inv * gam[1];
        float v2 = acc[mi][2][r] * inv * gam[2];
        float v3 = acc[mi][3][r] * inv * gam[3];
        int2 pp = posv[row];
        float sx, cx, sy, cy;
        __sincosf((float)pp.x * invf, &sx, &cx);
        __sincosf((float)pp.y * invf, &sy, &cy);
        float o0 = v0 * cx - v1 * sx, o1 = v1 * cx + v0 * sx;
        float o2 = v2 * cy - v3 * sy, o3 = v3 * cy + v2 * sy;
        int s = row & 1023, bb = row >> 10;
        short* base = dst + ((size_t)((bb * nh + h) * 1024 + s)) * 64;
        base[lr]      = f2bf(o0);
        base[lr + 16] = f2bf(o1);
        base[lr + 32] = f2bf(o2);
        base[lr + 48] = f2bf(o3);
      }
    }
  } else {
    // V: rms-norm (no gamma), write transposed [*, d, s] (short4 over s)
    int hk = g - 24;
#pragma unroll
    for (int mi = 0; mi < 4; ++mi) {
      f32x4 ss = acc[mi][0] * acc[mi][0];
#pragma unroll
      for (int ni = 1; ni < 4; ++ni) ss += acc[mi][ni] * acc[mi][ni];
#pragma unroll
      for (int m2 = 1; m2 < 16; m2 <<= 1)
#pragma unroll
        for (int r = 0; r < 4; ++r) ss[r] += __shfl_xor(ss[r], m2);
      f32x4 inv;
#pragma unroll
      for (int r = 0; r < 4; ++r) inv[r] = rsqrtf(ss[r] * 0.015625f + 1e-6f);
      int row = row0 + mi * 16 + lg * 4;
      int s0 = row & 1023, bb = row >> 10;
#pragma unroll
      for (int ni = 0; ni < 4; ++ni) {
        short4 sv;
        sv.x = f2bf(acc[mi][ni][0] * inv[0]);
        sv.y = f2bf(acc[mi][ni][1] * inv[1]);
        sv.z = f2bf(acc[mi][ni][2] * inv[2]);
        sv.w = f2bf(acc[mi][ni][3] * inv[3]);
        int d = ni * 16 + lr;
        *(short4*)&Vt[((size_t)((bb * 8 + hk) * 64 + d)) * 1024 + s0] = sv;
      }
    }
  }
}

// ---------------- 128x64-tile GEMM (out-proj) ----------------
__global__ __launch_bounds__(256) void gemm_bf16_bn64(
    const short* __restrict__ A, const short* __restrict__ BT,
    float* __restrict__ C, int M, int N, int K) {
  __shared__ short As[128 * 32];
  __shared__ short Bs[64 * 32];
  int wg = blockIdx.x + gridDim.x * blockIdx.y;      // nwg = 512
  int lid = (wg & 7) * 64 + (wg >> 3);
  int m0 = (lid & 31) * 128, n0 = (lid >> 5) * 64;
  int t = threadIdx.x;
  int w = t >> 6, lane = t & 63;
  int lr = lane & 15, lg = lane >> 4;

  f32x4 acc[2][4] = {};

  for (int k0 = 0; k0 < K; k0 += 32) {
    __syncthreads();
#pragma unroll
    for (int i = 0; i < 2; ++i) {
      int c = t + 256 * i;
      gload_lds16(A + (size_t)(m0 + (c >> 2)) * K + k0 + (c & 3) * 8, &As[c * 8]);
    }
    gload_lds16(BT + (size_t)(n0 + (t >> 2)) * K + k0 + (t & 3) * 8, &Bs[t * 8]);
    __syncthreads();
    short8 af[2], bf[4];
#pragma unroll
    for (int mi = 0; mi < 2; ++mi)
      af[mi] = *(const short8*)&As[(w * 32 + mi * 16 + lr) * 32 + lg * 8];
#pragma unroll
    for (int ni = 0; ni < 4; ++ni)
      bf[ni] = *(const short8*)&Bs[(ni * 16 + lr) * 32 + lg * 8];
    __builtin_amdgcn_s_setprio(1);
#pragma unroll
    for (int mi = 0; mi < 2; ++mi)
#pragma unroll
      for (int ni = 0; ni < 4; ++ni)
        acc[mi][ni] = MFMA16(af[mi], bf[ni], acc[mi][ni]);
    __builtin_amdgcn_s_setprio(0);
  }
#pragma unroll
  for (int mi = 0; mi < 2; ++mi)
#pragma unroll
    for (int ni = 0; ni < 4; ++ni) {
      int row = m0 + w * 32 + mi * 16 + lg * 4;
      int col = n0 + ni * 16 + lr;
#pragma unroll
      for (int r = 0; r < 4; ++r)
        C[(size_t)(row + r) * N + col] = acc[mi][ni][r];
    }
}

// ------------- attention v7: 2-phase LDS pipeline + XOR-swizzled subtiles -------------
// grid 1024 = B*H*(S/64), XCD-pinned per (b,h). 4 waves; wave w = q rows [qb*64+w*16,+16)
// over full kv. Per 64-kv tile: double-buffered DMA staging (stage t+1 overlaps
// compute t, ONE barrier per tile). 16B chunks placed at slot c^((row>>1)&3)
// (inverse-swizzled global source, linear LDS dest), ds_read applies same XOR:
// 16 lr-rows spread over all 8 bank-quads -> 2-way (free) instead of 8-way.
__global__ __launch_bounds__(256) void attn_kernel(
    const short* __restrict__ Qp, const short* __restrict__ Kp,
    const short* __restrict__ Vt, short* __restrict__ attn) {
  __shared__ short Ks[2][4096];   // [buf][f*2048 + kv*32 + chunk*8]
  __shared__ short Vs[2][4096];   // [buf][kvs*2048 + d*32 + chunk*8]
  int wg = blockIdx.x;
  int xcd = wg & 7, slot = wg >> 3;        // 0..127
  int group = xcd * 8 + (slot >> 4);       // 0..63 = (b,h)
  int qb = slot & 15;
  int b = group >> 4, h = group & 15;
  int hk = h >> 1;
  int t = threadIdx.x;
  int w = t >> 6, lane = t & 63;
  int lr = lane & 15, lg = lane >> 4;
  int q0 = qb * 64 + w * 16;

  const short* Qb = Qp + ((size_t)(b * 16 + h) * 1024) * 64;
  const short* Kb = Kp + ((size_t)(b * 8 + hk) * 1024) * 64;
  const short* Vb = Vt + ((size_t)(b * 8 + hk) * 64) * 1024;

  short8 qf[2];
#pragma unroll
  for (int f = 0; f < 2; ++f)
    qf[f] = *(const short8*)&Qb[(q0 + lr) * 64 + f * 32 + lg * 8];

  f32x4 acc[4] = {};   // [db]: out^T[d=db*16+lg*4+r][q=lr]
  float lsum = 0.0f;
  int co = (lg ^ ((lr >> 1) & 3)) * 8;   // swizzled chunk offset for reads

  auto STAGE = [&](short* ksb, short* vsb, int kt) {
    int kv0 = kt * 64;
#pragma unroll
    for (int i = 0; i < 2; ++i) {
      int q = t + 256 * i;
      int f = q >> 8, rem = q & 255, kv = rem >> 2, cslot = rem & 3;
      int csrc = cslot ^ ((kv >> 1) & 3);
      gload_lds16(Kb + (size_t)(kv0 + kv) * 64 + f * 32 + csrc * 8, &ksb[q * 8]);
    }
#pragma unroll
    for (int i = 0; i < 2; ++i) {
      int q = t + 256 * i;
      int kvs = q >> 8, rem = q & 255, d = rem >> 2, cslot = rem & 3;
      int csrc = cslot ^ ((d >> 1) & 3);
      gload_lds16(Vb + (size_t)d * 1024 + kv0 + kvs * 32 + csrc * 8, &vsb[q * 8]);
    }
  };

  auto COMPUTE = [&](const short* ksb, const short* vsb) {
    f32x4 sv[4];
    __builtin_amdgcn_s_setprio(1);
#pragma unroll
    for (int kvb = 0; kvb < 4; ++kvb) {
      int ro = (kvb * 16 + lr) * 32 + co;
      short8 a0 = *(const short8*)&ksb[ro];
      short8 a1 = *(const short8*)&ksb[2048 + ro];
      f32x4 s = {};
      s = MFMA16(a0, qf[0], s);
      s = MFMA16(a1, qf[1], s);
      sv[kvb] = s;
    }
    __builtin_amdgcn_s_setprio(0);
    uint32_t pk[4][2];
#pragma unroll
    for (int kvb = 0; kvb < 4; ++kvb) {
      float p0 = __expf(sv[kvb][0]), p1 = __expf(sv[kvb][1]);
      float p2 = __expf(sv[kvb][2]), p3 = __expf(sv[kvb][3]);
      lsum += (p0 + p1) + (p2 + p3);
      pk[kvb][0] = pack_bf2(p0, p1);
      pk[kvb][1] = pack_bf2(p2, p3);
    }
#pragma unroll
    for (int kvs = 0; kvs < 2; ++kvs) {
      union { uint32_t u[4]; short8 s; } pb;
#pragma unroll
      for (int j2 = 0; j2 < 4; ++j2) {
        int src = (2 * (lg & 1) + (j2 >> 1)) * 16 + lr;
        uint32_t lo = (uint32_t)__shfl((int)pk[kvs * 2 + 0][j2 & 1], src);
        uint32_t hi = (uint32_t)__shfl((int)pk[kvs * 2 + 1][j2 & 1], src);
        pb.u[j2] = (lg >= 2) ? hi : lo;
      }
      __builtin_amdgcn_s_setprio(1);
#pragma unroll
      for (int db = 0; db < 4; ++db) {
        short8 vf = *(const short8*)&vsb[kvs * 2048 + (db * 16 + lr) * 32 + co];
        acc[db] = MFMA16(vf, pb.s, acc[db]);
      }
      __builtin_amdgcn_s_setprio(0);
    }
  };

  STAGE(Ks[0], Vs[0], 0);
  __syncthreads();                  // drains vmcnt: tile 0 ready
  int cur = 0;
  for (int kt = 0; kt < 15; ++kt) {
    STAGE(Ks[cur ^ 1], Vs[cur ^ 1], kt + 1);   // overlaps with compute below
    __builtin_amdgcn_sched_barrier(0);
    COMPUTE(Ks[cur], Vs[cur]);
    __syncthreads();                // vmcnt(0)+lgkm drain: next tile ready
    cur ^= 1;
  }
  COMPUTE(Ks[cur], Vs[cur]);

  // ---- epilogue ----
  lsum += __shfl_xor(lsum, 16);
  lsum += __shfl_xor(lsum, 32);
  float inv = 1.0f / lsum;
  size_t rowbase = ((size_t)(b * 1024 + q0 + lr)) * 1024 + h * 64;
#pragma unroll
  for (int db = 0; db < 4; ++db) {
    uint32_t w0 = pack_bf2(acc[db][0] * inv, acc[db][1] * inv);
    uint32_t w1 = pack_bf2(acc[db][2] * inv, acc[db][3] * inv);
    uint32_t* pp = (uint32_t*)&attn[rowbase + db * 16 + lg * 4];
    pp[0] = w0;
    pp[1] = w1;
  }
}

extern "C" void kernel_launch(void* const* d_in, const int* in_sizes, int n_in,
                              void* d_out, int out_size, void* d_ws, size_t ws_size,
                              hipStream_t stream) {
  const float* X  = (const float*)d_in[0];
  const float* Wq = (const float*)d_in[1];
  const float* Wk = (const float*)d_in[2];
  const float* Wv = (const float*)d_in[3];
  const float* Wo = (const float*)d_in[4];
  const float* qg = (const float*)d_in[5];
  const float* kg = (const float*)d_in[6];
  const int* pos  = (const int*)d_in[7];
  float* out = (float*)d_out;

  char* ws = (char*)d_ws;
  short* XB    = (short*)(ws);                       // 8 MB  X bf16
  short* WTQKV = (short*)(ws + ((size_t)8 << 20));   // 4 MB  [Wq^T;Wk^T;Wv^T]
  short* WOT   = (short*)(ws + ((size_t)12 << 20));  // 2 MB  Wo^T
  short* QP    = (short*)(ws + ((size_t)14 << 20));  // 8 MB
  short* KP    = (short*)(ws + ((size_t)22 << 20));  // 4 MB
  short* VT    = (short*)(ws + ((size_t)26 << 20));  // 4 MB
  short* ATT   = (short*)(ws + ((size_t)30 << 20));  // 8 MB -> 38 MB total

  convert_bf16_kernel<<<4096, 256, 0, stream>>>(X, XB, 1048576);
  transpose_all_kernel<<<dim3(32, 96), dim3(32, 8), 0, stream>>>(Wq, Wk, Wv, Wo, WTQKV, WOT);

  gemm_qkv_fused<<<dim3(32, 16), 256, 0, stream>>>(XB, WTQKV, qg, kg, pos, QP, KP, VT);
  attn_kernel<<<1024, 256, 0, stream>>>(QP, KP, VT, ATT);
  gemm_bf16_bn64<<<dim3(32, 16), 256, 0, stream>>>(ATT, WOT, out, 4096, 1024, 1024);
}